// Round 9
// baseline (115.743 us; speedup 1.0000x reference)
//
#include <hip/hip_runtime.h>

// TensorProduct: out[z, o*U+u] = sum_{p: idx_out[p]==o} coeffs[p] * x0[z, idx0[p]*U+u] * x1[z, idx1[p]*U+u]
// Z=16384, U=128, NSEG=(32,8,32), P=128, all f32. Measured HBM ~436 MB -> ~80-90 us floor.
// R8 (109 us): occupancy 72%, no pipe saturated -> block churn + per-tile stage exposure.
// R9 = only proven pieces: R5's persistent dbuf structure (passed) + R8's LDS-meta
// compute loop (passed). 768 persistent blocks (3/CU), grid-stride over 16384 z-rows,
// 2x20KB double buffer, blob staged once. R7's readlane path stays shelved.

#define Z_DIM 16384
#define U_DIM 128
#define NSEG0 32
#define NSEG1 8
#define NSEG2 32
#define P_DIM 128
#define BLK   512
#define NBLOCKS 768                  // 3 blocks/CU * 256 CU

#define X0_FLOATS (NSEG0 * U_DIM)    // 4096 floats (16 KB)
#define X1_FLOATS (NSEG1 * U_DIM)    // 1024 floats (4 KB)
#define BUF_FLOATS (X0_FLOATS + X1_FLOATS) // 5120 floats (20 KB)

// blob layout (ints): [0..32] seg offsets, [33..39] pad, [40..295] meta int2[128], [296..303] pad
#define META_BASE 40
#define BLOB_INTS 304                // 1216 B = 76 * 16 B

typedef float f32x4 __attribute__((ext_vector_type(4)));

// ---------- setup: group the P terms by output segment into the ws blob ----------
__global__ __launch_bounds__(128) void tp_setup(
    const float* __restrict__ coeffs,
    const int* __restrict__ idx0,
    const int* __restrict__ idx1,
    const int* __restrict__ idx_out,
    int* __restrict__ blob)
{
    __shared__ int s_cnt[NSEG2];
    __shared__ int s_off[NSEG2 + 1];
    const int t = threadIdx.x;            // exactly P_DIM threads
    if (t < NSEG2) s_cnt[t] = 0;
    __syncthreads();
    const int o = idx_out[t];
    const int r = atomicAdd(&s_cnt[o], 1);
    __syncthreads();
    if (t == 0) {
        int sum = 0;
        for (int i = 0; i < NSEG2; ++i) { s_off[i] = sum; sum += s_cnt[i]; }
        s_off[NSEG2] = sum;
    }
    __syncthreads();
    // byte offsets within a z-slice: i0*512 <= 15872, i1*512 <= 3584 (fit 16b each)
    const int d = s_off[o] + r;
    int2* meta = reinterpret_cast<int2*>(blob + META_BASE);
    meta[d] = make_int2((idx0[t] * (U_DIM * 4)) | ((idx1[t] * (U_DIM * 4)) << 16),
                        __float_as_int(coeffs[t]));
    if (t <= NSEG2) blob[t] = s_off[t];
    if (t >= 33 && t < META_BASE) blob[t] = 0;                       // pad
    if (t >= 296 && t < BLOB_INTS) blob[t] = 0;                      // tail pad
}

// ---------- staging: async global->LDS, linear layout, 16 B/lane ----------
__device__ __forceinline__ void stage_tile(const float* __restrict__ x0,
                                           const float* __restrict__ x1,
                                           float* lbuf, size_t z, int t)
{
    const float4* g0 = reinterpret_cast<const float4*>(x0 + z * (size_t)X0_FLOATS);
    const float4* g1 = reinterpret_cast<const float4*>(x1 + z * (size_t)X1_FLOATS);
    float4* l0 = reinterpret_cast<float4*>(lbuf);
    float4* l1 = reinterpret_cast<float4*>(lbuf + X0_FLOATS);
    #pragma unroll
    for (int i = 0; i < (X0_FLOATS / 4) / BLK; ++i)   // 2 iters
        __builtin_amdgcn_global_load_lds(
            (const __attribute__((address_space(1))) void*)(g0 + i * BLK + t),
            (__attribute__((address_space(3))) void*)(l0 + i * BLK + t),
            16, 0, 0);
    if (t < X1_FLOATS / 4)                             // 256 lanes
        __builtin_amdgcn_global_load_lds(
            (const __attribute__((address_space(1))) void*)(g1 + t),
            (__attribute__((address_space(3))) void*)(l1 + t),
            16, 0, 0);
}

// ---------- main: persistent, grid-stride, double-buffered ----------
__global__ __launch_bounds__(BLK, 8) void tp_kernel(
    const float* __restrict__ x0,
    const float* __restrict__ x1,
    const int* __restrict__ blob_g,
    float* __restrict__ out)
{
    __shared__ float buf[2][BUF_FLOATS];  // 40 KB
    __shared__ int   s_blob[BLOB_INTS];   // ~1.2 KB   -> 42.2 KB total, 3 blocks/CU

    const int t = threadIdx.x;

    // --- prologue: stage blob (once) + first tile ---
    {
        const float4* gb = reinterpret_cast<const float4*>(blob_g);
        float4* lb = reinterpret_cast<float4*>(s_blob);
        if (t < BLOB_INTS / 4)                         // 76 lanes
            __builtin_amdgcn_global_load_lds(
                (const __attribute__((address_space(1))) void*)(gb + t),
                (__attribute__((address_space(3))) void*)(lb + t),
                16, 0, 0);
    }
    stage_tile(x0, x1, &buf[0][0], (size_t)blockIdx.x, t);

    // --- compute mapping (R8-proven): 8 waves x 4 segments; half owns 2 segments ---
    const int w  = t >> 6;                // wave 0..7
    const int h  = (t >> 5) & 1;          // lane half
    const int uq = t & 31;                // float4 column
    const int seg0 = 4 * w + 2 * h;

    int cur = 0;
    for (int tile = blockIdx.x; tile < Z_DIM; tile += NBLOCKS) {
        __syncthreads();   // own gload_lds drained (vmcnt0 before barrier);
                           // all waves done reading buf[cur^1] of previous tile

        if (tile + NBLOCKS < Z_DIM)
            stage_tile(x0, x1, &buf[cur ^ 1][0], (size_t)(tile + NBLOCKS), t);

        // --- compute tile from buf[cur] ---
        const char* x0base = reinterpret_cast<const char*>(&buf[cur][uq * 4]);
        const char* x1base = reinterpret_cast<const char*>(&buf[cur][X0_FLOATS + uq * 4]);
        const int2* s_meta = reinterpret_cast<const int2*>(s_blob + META_BASE);
        float* orow = out + (size_t)tile * (NSEG2 * U_DIM) + uq * 4;

        const int b = s_blob[seg0];       // half-divergent bounds (2-valued), benign
        const int m = s_blob[seg0 + 1];
        const int e = s_blob[seg0 + 2];

        int sb = b;
        #pragma unroll
        for (int oo = 0; oo < 2; ++oo) {
            const int se = (oo == 0) ? m : e;
            f32x4 acc = (f32x4)0.f;
            int2 mt = s_meta[sb];         // s_meta[128] is zeroed pad, in-bounds
            for (int k = sb; k < se; ++k) {
                const int2 mn = s_meta[k + 1];        // depth-1 meta prefetch
                const float c = __int_as_float(mt.y);
                const f32x4 a = *reinterpret_cast<const f32x4*>(x0base + (mt.x & 0xffff));
                const f32x4 v = *reinterpret_cast<const f32x4*>(x1base + ((unsigned)mt.x >> 16));
                acc += a * v * c;         // contracts to v_fma
                mt = mn;
            }
            __builtin_nontemporal_store(acc,
                reinterpret_cast<f32x4*>(orow + (seg0 + oo) * U_DIM));
            sb = se;
        }
        cur ^= 1;
    }
}

extern "C" void kernel_launch(void* const* d_in, const int* in_sizes, int n_in,
                              void* d_out, int out_size, void* d_ws, size_t ws_size,
                              hipStream_t stream) {
    const float* x0      = (const float*)d_in[0];
    const float* x1      = (const float*)d_in[1];
    const float* coeffs  = (const float*)d_in[2];
    const int*   idx0    = (const int*)d_in[3];
    const int*   idx1    = (const int*)d_in[4];
    const int*   idx_out = (const int*)d_in[5];
    float* out = (float*)d_out;

    int* blob = (int*)d_ws;   // BLOB_INTS ints, 16B-aligned

    tp_setup<<<1, P_DIM, 0, stream>>>(coeffs, idx0, idx1, idx_out, blob);
    tp_kernel<<<NBLOCKS, BLK, 0, stream>>>(x0, x1, blob, out);
}